// Round 6
// baseline (341.617 us; speedup 1.0000x reference)
//
#include <hip/hip_runtime.h>
#include <hip/hip_bf16.h>
#include <hip/hip_cooperative_groups.h>

namespace cg = cooperative_groups;

#define DD 32
#define P_MAX 118
#define N_MAX 236
#define TBL (P_MAX * N_MAX)

// native clang vector types for nontemporal builtins (HIP_vector_type invalid)
typedef int   ivec4 __attribute__((ext_vector_type(4)));
typedef float fvec4 __attribute__((ext_vector_type(4)));

// ws float offsets
#define PST 0                       // proton states  118*32
#define NST (P_MAX * DD)            // neutron states 236*32 at 3776
#define UOF ((P_MAX + N_MAX) * DD)  // U_T 32x118 at 11328
#define VOF (UOF + DD * P_MAX)      // V_T 32x236 at 15104
#define TOF (VOF + DD * N_MAX)      // table (float2) at 22656 floats

#define FGRID 512
#define FBLK  256
#define FTHREADS (FGRID * FBLK)

// ---------------------------------------------------------------------------
// Kernel 1: the two sequential SiLU-matvec chains. OWN kernel, 2 blocks x 64,
// no VGPR cap (R5 lesson: sharing a kernel with register-hungry phases made
// the compiler spill w[32] -> 107us). Critical path: VALU-only readlane
// broadcast + fmac; issue-bound at ~140 cyc/step -> ~14us for 236 steps.
// ---------------------------------------------------------------------------
__global__ __launch_bounds__(64) void chain_kernel(
    const float* __restrict__ emb,
    const float* __restrict__ Wp, const float* __restrict__ bp,
    const float* __restrict__ Wn, const float* __restrict__ bn,
    float* __restrict__ ws)
{
    const int lane = threadIdx.x;
    const int ch = lane & 31;

    const float* W;
    const float* b;
    const float* e0;
    float* out;
    int len;
    if (blockIdx.x == 0) {
        W = Wp; b = bp; e0 = emb;       out = ws + PST; len = P_MAX;
    } else {
        W = Wn; b = bn; e0 = emb + DD;  out = ws + NST; len = N_MAX;
    }

    float w[32];
#pragma unroll
    for (int q = 0; q < 8; ++q) {
        float4 v = reinterpret_cast<const float4*>(W + ch * 32)[q];
        w[4 * q + 0] = v.x; w[4 * q + 1] = v.y;
        w[4 * q + 2] = v.z; w[4 * q + 3] = v.w;
    }
    const float bias = b[ch];
    float p = e0[ch];

    for (int t = 0; t < len; ++t) {
        float e = __expf(-p);
        float s = p * __builtin_amdgcn_rcpf(1.0f + e);
        int sb = __float_as_int(s);

        float a0 = 0.0f, a1 = 0.0f, a2 = 0.0f, a3 = 0.0f;
#pragma unroll
        for (int k = 0; k < 32; k += 4) {
            a0 += __int_as_float(__builtin_amdgcn_readlane(sb, k + 0)) * w[k + 0];
            a1 += __int_as_float(__builtin_amdgcn_readlane(sb, k + 1)) * w[k + 1];
            a2 += __int_as_float(__builtin_amdgcn_readlane(sb, k + 2)) * w[k + 2];
            a3 += __int_as_float(__builtin_amdgcn_readlane(sb, k + 3)) * w[k + 3];
        }
        p = bias + ((a0 + a1) + (a2 + a3));
        if (lane < 32) out[t * DD + ch] = p;
    }
}

// ---------------------------------------------------------------------------
// Kernel 2 (cooperative): uv -> grid.sync -> table -> grid.sync -> gather.
// 512 blocks x 256 threads; __launch_bounds__(256,2) -> 2 blocks/CU
// co-residency needs VGPR<=256 (compiler will pick ~64 -> huge margin).
// Collapses 3 dispatches into 1: two launch gaps + cold-starts removed.
// ---------------------------------------------------------------------------
__global__ __launch_bounds__(FBLK, 2) void fused_kernel(
    const float* __restrict__ W1, const float* __restrict__ b1,
    const float* __restrict__ ln_g, const float* __restrict__ ln_b,
    const float* __restrict__ W2, const float* __restrict__ b2,
    const float* __restrict__ Wr, const float* __restrict__ br,
    const ivec4* __restrict__ x4,
    float* __restrict__ ws,
    fvec4* __restrict__ out4,
    int B4)
{
    cg::grid_group grid = cg::this_grid();
    const int tid = blockIdx.x * FBLK + threadIdx.x;

    // ---- phase 1: uv. 192 tasks = (j in [0,32)) x (bx in [0,6)),
    //      one per wave; waves 0..191 live in blocks 0..47.
    {
        const int wv = (blockIdx.x << 2) | (threadIdx.x >> 6);
        if (wv < 192) {
            const int lane = threadIdx.x & 63;
            const int j  = wv / 6;
            const int bx = wv - 6 * j;
            const bool prot = bx < 2;
            const int t = prot ? bx * 64 + lane : (bx - 2) * 64 + lane;
            const int len = prot ? P_MAX : N_MAX;
            if (t < len) {
                const float* st = ws + (prot ? PST : NST) + t * DD;
                const float* wr = W1 + j * 64 + (prot ? 0 : 32);
                float acc = prot ? 0.0f : b1[j];
#pragma unroll
                for (int q = 0; q < 8; ++q) {
                    float4 s4 = reinterpret_cast<const float4*>(st)[q];
                    acc = fmaf(s4.x, wr[4 * q + 0], acc);
                    acc = fmaf(s4.y, wr[4 * q + 1], acc);
                    acc = fmaf(s4.z, wr[4 * q + 2], acc);
                    acc = fmaf(s4.w, wr[4 * q + 3], acc);
                }
                if (prot) ws[UOF + j * P_MAX + t] = acc;
                else      ws[VOF + j * N_MAX + t] = acc;
            }
        }
    }

    __threadfence();
    grid.sync();

    // ---- phase 2: table. One entry per thread (131072 threads >= 27848).
    float2* table = (float2*)(ws + TOF);
    if (tid < TBL) {
        const int e = tid;
        const int pi = e / N_MAX;
        const int ni = e - pi * N_MAX;

        const float* UT = ws + UOF;   // 32 x 118
        const float* VT = ws + VOF;   // 32 x 236

        float h[32];
        float mu = 0.0f;
#pragma unroll
        for (int j = 0; j < 32; ++j) {
            float a = UT[j * P_MAX + pi] + VT[j * N_MAX + ni];
            float ee = __expf(-a);
            float s = a * __builtin_amdgcn_rcpf(1.0f + ee);
            h[j] = s;
            mu += s;
        }
        mu *= (1.0f / 32.0f);
        float var = 0.0f;
#pragma unroll
        for (int j = 0; j < 32; ++j) {
            float d = h[j] - mu;
            var = fmaf(d, d, var);
        }
        var *= (1.0f / 32.0f);
        const float inv = __builtin_amdgcn_rsqf(var + 1e-5f);
#pragma unroll
        for (int j = 0; j < 32; ++j)
            h[j] = (h[j] - mu) * inv * ln_g[j] + ln_b[j];

        float h2[32];
#pragma unroll
        for (int j0 = 0; j0 < 32; j0 += 8) {
            float acc[8];
#pragma unroll
            for (int u = 0; u < 8; ++u) acc[u] = b2[j0 + u];
#pragma unroll
            for (int k = 0; k < 32; ++k) {
#pragma unroll
                for (int u = 0; u < 8; ++u)
                    acc[u] = fmaf(h[k], W2[(j0 + u) * 32 + k], acc[u]);
            }
#pragma unroll
            for (int u = 0; u < 8; ++u) h2[j0 + u] = acc[u];
        }

        float o0 = br[0], o1 = br[1];
        float p0 = 0.0f, p1 = 0.0f;
#pragma unroll
        for (int k = 0; k < 32; k += 2) {
            o0 = fmaf(h2[k], Wr[k], o0);
            p0 = fmaf(h2[k + 1], Wr[k + 1], p0);
            o1 = fmaf(h2[k], Wr[32 + k], o1);
            p1 = fmaf(h2[k + 1], Wr[32 + k + 1], p1);
        }
        table[e] = make_float2(o0 + p0, o1 + p1);
    }

    __threadfence();
    grid.sync();

    // ---- phase 3: gather. Grid-stride over B4 4-sample units.
    //      Nontemporal on x/out streams so L2 stays dedicated to the table.
    const float2* tbl = (const float2*)(ws + TOF);
    for (int i = tid; i < B4; i += FTHREADS) {
        ivec4 a = __builtin_nontemporal_load(x4 + 2 * i);
        ivec4 b = __builtin_nontemporal_load(x4 + 2 * i + 1);
        float2 t0 = tbl[(a.x - 1) * N_MAX + (a.y - 1)];
        float2 t1 = tbl[(a.z - 1) * N_MAX + (a.w - 1)];
        float2 t2 = tbl[(b.x - 1) * N_MAX + (b.y - 1)];
        float2 t3 = tbl[(b.z - 1) * N_MAX + (b.w - 1)];
        fvec4 o0v = {t0.x, t0.y, t1.x, t1.y};
        fvec4 o1v = {t2.x, t2.y, t3.x, t3.y};
        __builtin_nontemporal_store(o0v, out4 + 2 * i);
        __builtin_nontemporal_store(o1v, out4 + 2 * i + 1);
    }
}

extern "C" void kernel_launch(void* const* d_in, const int* in_sizes, int n_in,
                              void* d_out, int out_size, void* d_ws, size_t ws_size,
                              hipStream_t stream) {
    const int*   x    = (const int*)d_in[0];
    const float* emb  = (const float*)d_in[1];
    const float* Wp   = (const float*)d_in[2];
    const float* bp   = (const float*)d_in[3];
    const float* Wn   = (const float*)d_in[4];
    const float* bn   = (const float*)d_in[5];
    const float* W1   = (const float*)d_in[6];
    const float* b1   = (const float*)d_in[7];
    const float* ln_g = (const float*)d_in[8];
    const float* ln_b = (const float*)d_in[9];
    const float* W2   = (const float*)d_in[10];
    const float* b2   = (const float*)d_in[11];
    const float* Wr   = (const float*)d_in[12];
    const float* br   = (const float*)d_in[13];

    const int B = in_sizes[0] / 2;
    int B4 = B / 4;

    float* wsf = (float*)d_ws;

    chain_kernel<<<2, 64, 0, stream>>>(emb, Wp, bp, Wn, bn, wsf);

    const ivec4* x4 = (const ivec4*)x;
    fvec4* out4 = (fvec4*)d_out;
    void* args[] = {
        (void*)&W1, (void*)&b1, (void*)&ln_g, (void*)&ln_b,
        (void*)&W2, (void*)&b2, (void*)&Wr, (void*)&br,
        (void*)&x4, (void*)&wsf, (void*)&out4, (void*)&B4
    };
    hipLaunchCooperativeKernel((void*)fused_kernel, dim3(FGRID), dim3(FBLK),
                               args, 0, stream);
}

// Round 7
// 168.743 us; speedup vs baseline: 2.0245x; 2.0245x over previous
//
#include <hip/hip_runtime.h>
#include <hip/hip_bf16.h>

#define DD 32
#define P_MAX 118
#define N_MAX 236
#define TBL (P_MAX * N_MAX)

// native clang vector types for nontemporal builtins (HIP_vector_type invalid)
typedef int   ivec4 __attribute__((ext_vector_type(4)));
typedef float fvec4 __attribute__((ext_vector_type(4)));

// ws float offsets
#define PST 0                       // proton states  118*32
#define NST (P_MAX * DD)            // neutron states 236*32 at 3776
#define UOF ((P_MAX + N_MAX) * DD)  // U_T 32x118 at 11328
#define VOF (UOF + DD * P_MAX)      // V_T 32x236 at 15104
#define TOF (VOF + DD * N_MAX)      // table (float2) at 22656 floats

// ---------------------------------------------------------------------------
// Kernel A: chain + own-side UV, partitioned by side -> no cross-block dep.
// 2 blocks x 256 threads. Block s: wave 0 runs side-s chain (118/236 steps);
// __syncthreads(); all 4 waves compute side-s uv tasks (64 U / 128 V).
// __launch_bounds__(256,1): VGPR budget up to 512 -> chain's w[32] cannot
// spill (R5 lesson: 1024-thread bound capped VGPR at 64 -> scratch thrash,
// FETCH_SIZE 114 MB, 107us). States are read back through same-CU L1.
// ---------------------------------------------------------------------------
__global__ __launch_bounds__(256, 1) void chain_uv_kernel(
    const float* __restrict__ emb,
    const float* __restrict__ Wp, const float* __restrict__ bp,
    const float* __restrict__ Wn, const float* __restrict__ bn,
    const float* __restrict__ W1, const float* __restrict__ b1,
    float* __restrict__ ws)
{
    const int side = blockIdx.x;          // 0 = proton, 1 = neutron
    const int wid  = threadIdx.x >> 6;
    const int lane = threadIdx.x & 63;

    // ---- phase 1: chain on wave 0 ----
    if (wid == 0) {
        const float* W  = side ? Wn : Wp;
        const float* b  = side ? bn : bp;
        const float* e0 = emb + side * DD;
        float* out      = ws + (side ? NST : PST);
        const int len   = side ? N_MAX : P_MAX;
        const int ch    = lane & 31;

        float w[32];
#pragma unroll
        for (int q = 0; q < 8; ++q) {
            float4 v = reinterpret_cast<const float4*>(W + ch * 32)[q];
            w[4 * q + 0] = v.x; w[4 * q + 1] = v.y;
            w[4 * q + 2] = v.z; w[4 * q + 3] = v.w;
        }
        const float bias = b[ch];
        float p = e0[ch];

        for (int t = 0; t < len; ++t) {
            float e = __expf(-p);
            float s = p * __builtin_amdgcn_rcpf(1.0f + e);
            int sb = __float_as_int(s);

            float a0 = 0.0f, a1 = 0.0f, a2 = 0.0f, a3 = 0.0f;
#pragma unroll
            for (int k = 0; k < 32; k += 4) {
                a0 += __int_as_float(__builtin_amdgcn_readlane(sb, k + 0)) * w[k + 0];
                a1 += __int_as_float(__builtin_amdgcn_readlane(sb, k + 1)) * w[k + 1];
                a2 += __int_as_float(__builtin_amdgcn_readlane(sb, k + 2)) * w[k + 2];
                a3 += __int_as_float(__builtin_amdgcn_readlane(sb, k + 3)) * w[k + 3];
            }
            p = bias + ((a0 + a1) + (a2 + a3));
            if (lane < 32) out[t * DD + ch] = p;
        }
    }

    __syncthreads();

    // ---- phase 2: own-side uv ----
    // proton: 64 tasks (j in [0,32), bx in {0,1}), 16 per wave
    // neutron: 128 tasks (j in [0,32), bx in {0..3}), 32 per wave
    const int tasks_per_wave = side ? 32 : 16;
    const int base = side ? NST : PST;
    const int len  = side ? N_MAX : P_MAX;
    for (int i = 0; i < tasks_per_wave; ++i) {
        const int tau = wid * tasks_per_wave + i;
        int j, bx;
        if (side) { j = tau >> 2; bx = tau & 3; }
        else      { j = tau >> 1; bx = tau & 1; }
        const int t = bx * 64 + lane;
        if (t >= len) continue;

        const float* st = ws + base + t * DD;
        const float* wr = W1 + j * 64 + (side ? 32 : 0);
        float acc = side ? b1[j] : 0.0f;
#pragma unroll
        for (int q = 0; q < 8; ++q) {
            float4 s4 = reinterpret_cast<const float4*>(st)[q];
            acc = fmaf(s4.x, wr[4 * q + 0], acc);
            acc = fmaf(s4.y, wr[4 * q + 1], acc);
            acc = fmaf(s4.z, wr[4 * q + 2], acc);
            acc = fmaf(s4.w, wr[4 * q + 3], acc);
        }
        if (side) ws[VOF + j * N_MAX + t] = acc;
        else      ws[UOF + j * P_MAX + t] = acc;
    }
}

// ---------------------------------------------------------------------------
// Kernel B (R4 control): build the table. Per thread:
//   h = silu(U_T[:,pi] + V_T[:,ni]); layernorm; W2 matvec; Wr readout.
// U reads broadcast, V reads coalesced.
// ---------------------------------------------------------------------------
__global__ __launch_bounds__(64, 1) void table_kernel(
    const float* __restrict__ ws,
    const float* __restrict__ ln_g, const float* __restrict__ ln_b,
    const float* __restrict__ W2, const float* __restrict__ b2,
    const float* __restrict__ Wr, const float* __restrict__ br,
    float2* __restrict__ table)
{
    const int e = blockIdx.x * 64 + threadIdx.x;
    if (e >= TBL) return;
    const int pi = e / N_MAX;
    const int ni = e - pi * N_MAX;

    const float* UT = ws + UOF;   // 32 x 118
    const float* VT = ws + VOF;   // 32 x 236

    float h[32];
    float mu = 0.0f;
#pragma unroll
    for (int j = 0; j < 32; ++j) {
        float a = UT[j * P_MAX + pi] + VT[j * N_MAX + ni];
        float ee = __expf(-a);
        float s = a * __builtin_amdgcn_rcpf(1.0f + ee);
        h[j] = s;
        mu += s;
    }
    mu *= (1.0f / 32.0f);
    float var = 0.0f;
#pragma unroll
    for (int j = 0; j < 32; ++j) {
        float d = h[j] - mu;
        var = fmaf(d, d, var);
    }
    var *= (1.0f / 32.0f);
    const float inv = __builtin_amdgcn_rsqf(var + 1e-5f);
#pragma unroll
    for (int j = 0; j < 32; ++j)
        h[j] = (h[j] - mu) * inv * ln_g[j] + ln_b[j];

    // h2 = h @ W2^T + b2
    float h2[32];
#pragma unroll
    for (int j0 = 0; j0 < 32; j0 += 8) {
        float acc[8];
#pragma unroll
        for (int u = 0; u < 8; ++u) acc[u] = b2[j0 + u];
#pragma unroll
        for (int k = 0; k < 32; ++k) {
#pragma unroll
            for (int u = 0; u < 8; ++u)
                acc[u] = fmaf(h[k], W2[(j0 + u) * 32 + k], acc[u]);
        }
#pragma unroll
        for (int u = 0; u < 8; ++u) h2[j0 + u] = acc[u];
    }

    float o0 = br[0], o1 = br[1];
    float p0 = 0.0f, p1 = 0.0f;
#pragma unroll
    for (int k = 0; k < 32; k += 2) {
        o0 = fmaf(h2[k], Wr[k], o0);
        p0 = fmaf(h2[k + 1], Wr[k + 1], p0);
        o1 = fmaf(h2[k], Wr[32 + k], o1);
        p1 = fmaf(h2[k + 1], Wr[32 + k + 1], p1);
    }
    table[e] = make_float2(o0 + p0, o1 + p1);
}

// ---------------------------------------------------------------------------
// Kernel C (R4 control): gather, 4 samples/thread. Nontemporal on the
// x/out streams (read/write-once, 8 MB each) so L2 stays dedicated to the
// 223 KB table.
// ---------------------------------------------------------------------------
__global__ __launch_bounds__(256) void gather_kernel(
    const ivec4* __restrict__ x4,
    const float2* __restrict__ table,
    fvec4* __restrict__ out4,
    int B4)
{
    const int i = blockIdx.x * 256 + threadIdx.x;
    if (i >= B4) return;
    ivec4 a = __builtin_nontemporal_load(x4 + 2 * i);
    ivec4 b = __builtin_nontemporal_load(x4 + 2 * i + 1);
    float2 t0 = table[(a.x - 1) * N_MAX + (a.y - 1)];
    float2 t1 = table[(a.z - 1) * N_MAX + (a.w - 1)];
    float2 t2 = table[(b.x - 1) * N_MAX + (b.y - 1)];
    float2 t3 = table[(b.z - 1) * N_MAX + (b.w - 1)];
    fvec4 o0v = {t0.x, t0.y, t1.x, t1.y};
    fvec4 o1v = {t2.x, t2.y, t3.x, t3.y};
    __builtin_nontemporal_store(o0v, out4 + 2 * i);
    __builtin_nontemporal_store(o1v, out4 + 2 * i + 1);
}

extern "C" void kernel_launch(void* const* d_in, const int* in_sizes, int n_in,
                              void* d_out, int out_size, void* d_ws, size_t ws_size,
                              hipStream_t stream) {
    const int*   x    = (const int*)d_in[0];
    const float* emb  = (const float*)d_in[1];
    const float* Wp   = (const float*)d_in[2];
    const float* bp   = (const float*)d_in[3];
    const float* Wn   = (const float*)d_in[4];
    const float* bn   = (const float*)d_in[5];
    const float* W1   = (const float*)d_in[6];
    const float* b1   = (const float*)d_in[7];
    const float* ln_g = (const float*)d_in[8];
    const float* ln_b = (const float*)d_in[9];
    const float* W2   = (const float*)d_in[10];
    const float* b2   = (const float*)d_in[11];
    const float* Wr   = (const float*)d_in[12];
    const float* br   = (const float*)d_in[13];

    const int B = in_sizes[0] / 2;

    float* wsf = (float*)d_ws;
    float2* table = (float2*)(wsf + TOF);

    chain_uv_kernel<<<2, 256, 0, stream>>>(emb, Wp, bp, Wn, bn, W1, b1, wsf);

    table_kernel<<<(TBL + 63) / 64, 64, 0, stream>>>(
        wsf, ln_g, ln_b, W2, b2, Wr, br, table);

    gather_kernel<<<(B / 4 + 255) / 256, 256, 0, stream>>>(
        (const ivec4*)x, table, (fvec4*)d_out, B / 4);
}